// Round 2
// baseline (1217.959 us; speedup 1.0000x reference)
//
#include <hip/hip_runtime.h>
#include <math.h>

// ---------------------------------------------------------------------------
// Workspace layout (floats):
//   [0..73)    : CG tensors (alpha-folded):
//                P0 @0 (1), P1 @1 (1x3x3), P2 @10 (3x1x3), P3 @19 (3x3x1), P4 @28 (3x5x3)
//   [128.. )   : node precompute table T [N][32][12] floats
// ---------------------------------------------------------------------------
#define WS_T_OFF 128

__device__ inline double dfact(int n) {
    double r = 1.0;
    for (int i = 2; i <= n; ++i) r *= (double)i;
    return r;
}

// real->complex spherical harmonic change of basis (e3nn convention)
__device__ void qmat(int l, double qr[5][5], double qi[5][5]) {
    for (int a = 0; a < 5; a++)
        for (int b = 0; b < 5; b++) { qr[a][b] = 0.0; qi[a][b] = 0.0; }
    const double inv = 0.70710678118654752440;
    for (int m = -l; m < 0; ++m) {
        qr[l + m][l - m] = inv;      // col l+|m|
        qi[l + m][l + m] = -inv;     // col l-|m|
    }
    qr[l][l] = 1.0;
    for (int m = 1; m <= l; ++m) {
        double sgn = (m & 1) ? -1.0 : 1.0;
        qr[l + m][l + m] = sgn * inv;
        qi[l + m][l - m] = sgn * inv;
    }
    // multiply by (-i)^l
    if (l == 1) {          // * (-i): (r,i) -> (i,-r)
        for (int a = 0; a < 5; a++)
            for (int b = 0; b < 5; b++) {
                double r = qr[a][b], im = qi[a][b];
                qr[a][b] = im; qi[a][b] = -r;
            }
    } else if (l == 2) {   // * (-1)
        for (int a = 0; a < 5; a++)
            for (int b = 0; b < 5; b++) { qr[a][b] = -qr[a][b]; qi[a][b] = -qi[a][b]; }
    }
}

__global__ void cg_init_kernel(float* __restrict__ cg_out) {
    if (threadIdx.x != 0 || blockIdx.x != 0) return;
    const int l1s[5] = {0, 0, 1, 1, 1};
    const int l2s[5] = {0, 1, 0, 1, 2};
    const int l3s[5] = {0, 1, 1, 0, 1};
    const int offs[5] = {0, 1, 10, 19, 28};
    // alpha = 1/sqrt(u*v*n_paths_to_out): out0 has 2 paths, out1 has 3
    const double alphas[5] = {0.125, 0.10206207261596575, 0.10206207261596575,
                              0.125, 0.10206207261596575};
    for (int p = 0; p < 5; ++p) {
        int l1 = l1s[p], l2 = l2s[p], l3 = l3s[p];
        int d1 = 2 * l1 + 1, d2 = 2 * l2 + 1, d3 = 2 * l3 + 1;
        double C[5][5][5];
        for (int a = 0; a < 5; a++)
            for (int b = 0; b < 5; b++)
                for (int c = 0; c < 5; c++) C[a][b][c] = 0.0;
        // SU(2) "CG" via the reference's exact (non-standard) Racah-form:
        // ALL six m-dependent factorials live in the NUMERATOR (unlike e3nn).
        for (int m1 = -l1; m1 <= l1; ++m1)
            for (int m2 = -l2; m2 <= l2; ++m2) {
                int m3 = m1 + m2;
                if (m3 < -l3 || m3 > l3) continue;
                int vmin = -l1 + l2 + m3;
                if (-l1 + m1 > vmin) vmin = -l1 + m1;
                if (0 > vmin) vmin = 0;
                int vmax = l2 + l3 + m1;
                if (l3 - l1 + l2 < vmax) vmax = l3 - l1 + l2;
                if (l3 + m3 < vmax) vmax = l3 + m3;
                double c = sqrt((double)(2 * l3 + 1) * dfact(l3 + l1 - l2) *
                                dfact(l3 - l1 + l2) * dfact(l1 + l2 - l3) /
                                dfact(l1 + l2 + l3 + 1));
                c *= sqrt(dfact(l3 + m3) * dfact(l3 - m3) * dfact(l1 - m1) *
                          dfact(l1 + m1) * dfact(l2 - m2) * dfact(l2 + m2));
                double s = 0.0;
                for (int v = vmin; v <= vmax; ++v) {
                    double term = dfact(l2 + l3 + m1 - v) * dfact(l1 - m1 + v) /
                                  (dfact(v) * dfact(l3 - l1 + l2 - v) *
                                   dfact(l3 + m3 - v) * dfact(v + l1 - l2 - m3));
                    if ((v + l2 + m2) & 1) term = -term;
                    s += term;
                }
                C[l1 + m1][l2 + m2][l3 + m3] = c * s;
            }
        double q1r[5][5], q1i[5][5], q2r[5][5], q2i[5][5], q3r[5][5], q3i[5][5];
        qmat(l1, q1r, q1i);
        qmat(l2, q2r, q2i);
        qmat(l3, q3r, q3i);
        // out[j,l,m] = Re( sum_{i,k,n} q1[i][j] q2[k][l] conj(q3[n][m]) C[i][k][n] )
        double outv[45];
        double norm2 = 0.0;
        for (int j = 0; j < d1; ++j)
            for (int l_ = 0; l_ < d2; ++l_)
                for (int m = 0; m < d3; ++m) {
                    double acc = 0.0;
                    for (int i = 0; i < d1; ++i)
                        for (int k = 0; k < d2; ++k)
                            for (int n = 0; n < d3; ++n) {
                                double ar = q1r[i][j], ai = q1i[i][j];
                                double br = q2r[k][l_], bi = q2i[k][l_];
                                double cr = q3r[n][m], ci = q3i[n][m];
                                double abr = ar * br - ai * bi;
                                double abi = ar * bi + ai * br;
                                double re = abr * cr + abi * ci;  // Re(ab*conj(c))
                                acc += re * C[i][k][n];
                            }
                    outv[(j * d2 + l_) * d3 + m] = acc;
                    norm2 += acc * acc;
                }
        double scale = alphas[p] / sqrt(norm2);
        for (int idx = 0; idx < d1 * d2 * d3; ++idx)
            cg_out[offs[p] + idx] = (float)(outv[idx] * scale);
    }
}

// ---------------------------------------------------------------------------
// Node precompute: T[n][w][12] = {a0, a1, b2[0..2], b3[0..2], b4[0..2], pad}
//   a0[w]   = sum_u s[u]   W0[u][w]
//   a1[w]   = sum_u s[u]   W1[u][w]
//   bp[w,i] = sum_u v[u,i] Wp[u][w]   (p = 2,3,4)
// ---------------------------------------------------------------------------
__global__ __launch_bounds__(256) void node_precompute(
    const float* __restrict__ feat, const float* __restrict__ W,
    float* __restrict__ T, int N) {
    int t = blockIdx.x * 256 + threadIdx.x;
    int n = t >> 5, w = t & 31;
    if (n >= N) return;
    const float* f = feat + (size_t)n * 128;
    float a0 = 0.f, a1 = 0.f;
    float b2x = 0.f, b2y = 0.f, b2z = 0.f;
    float b3x = 0.f, b3y = 0.f, b3z = 0.f;
    float b4x = 0.f, b4y = 0.f, b4z = 0.f;
#pragma unroll 8
    for (int u = 0; u < 32; ++u) {
        float s = f[u];
        float v0 = f[32 + 3 * u], v1 = f[33 + 3 * u], v2 = f[34 + 3 * u];
        float w0 = W[u * 32 + w];
        float w1 = W[1024 + u * 32 + w];
        float w2 = W[2048 + u * 32 + w];
        float w3 = W[3072 + u * 32 + w];
        float w4 = W[4096 + u * 32 + w];
        a0 = fmaf(s, w0, a0);
        a1 = fmaf(s, w1, a1);
        b2x = fmaf(v0, w2, b2x); b2y = fmaf(v1, w2, b2y); b2z = fmaf(v2, w2, b2z);
        b3x = fmaf(v0, w3, b3x); b3y = fmaf(v1, w3, b3y); b3z = fmaf(v2, w3, b3z);
        b4x = fmaf(v0, w4, b4x); b4y = fmaf(v1, w4, b4y); b4z = fmaf(v2, w4, b4z);
    }
    float4* Tp = (float4*)(T + (size_t)(n * 32 + w) * 12);
    Tp[0] = make_float4(a0, a1, b2x, b2y);
    Tp[1] = make_float4(b2z, b3x, b3y, b3z);
    Tp[2] = make_float4(b4x, b4y, b4z, 0.f);
}

// ---------------------------------------------------------------------------
// Edge kernel: 32 threads per edge (thread w), gather T[src], combine with sh,
// atomically scatter 128-float message to out[dst]. Generic CG contractions —
// no structural assumptions (the reference's CG diagonals are NON-uniform).
// ---------------------------------------------------------------------------
__global__ __launch_bounds__(256) void edge_kernel(
    const float* __restrict__ T, const float* __restrict__ sh,
    const int* __restrict__ eidx, const float* __restrict__ cg,
    float* __restrict__ out, int E) {
    int t = blockIdx.x * 256 + threadIdx.x;
    int e = t >> 5, w = t & 31;
    if (e >= E) return;
    int src = eidx[e];
    int dst = eidx[E + e];
    const float4* Tp = (const float4*)(T + (size_t)(src * 32 + w) * 12);
    float4 q0 = Tp[0], q1 = Tp[1], q2 = Tp[2];
    // a0=q0.x a1=q0.y b2={q0.z,q0.w,q1.x} b3={q1.y,q1.z,q1.w} b4={q2.x,q2.y,q2.z}
    const float* Ye = sh + (size_t)e * 9;
    float Y0 = Ye[0];
    float Y1v[3] = {Ye[1], Ye[2], Ye[3]};
    float Y2v[5] = {Ye[4], Ye[5], Ye[6], Ye[7], Ye[8]};

    // P0: out0 += cg0 * Y0 * a0
    float o0 = cg[0] * Y0 * q0.x;
    // P3: out0 += sum_{i,j} b3[i] * Y1v[j] * cg3[i*3+j]   (cg3 at offset 19, [3][3][1])
    float b3[3] = {q1.y, q1.z, q1.w};
#pragma unroll
    for (int i = 0; i < 3; ++i)
#pragma unroll
        for (int j = 0; j < 3; ++j)
            o0 = fmaf(b3[i] * Y1v[j], cg[19 + i * 3 + j], o0);

    // P1: out1[m] += a1 * sum_j Y1v[j] * cg1[j*3+m]       (cg1 at offset 1, [1][3][3])
    float ox = 0.f, oy = 0.f, oz = 0.f;
#pragma unroll
    for (int j = 0; j < 3; ++j) {
        float ay = q0.y * Y1v[j];
        ox = fmaf(ay, cg[1 + j * 3 + 0], ox);
        oy = fmaf(ay, cg[1 + j * 3 + 1], oy);
        oz = fmaf(ay, cg[1 + j * 3 + 2], oz);
    }
    // P2: out1[m] += Y0 * sum_i b2[i] * cg2[i*3+m]        (cg2 at offset 10, [3][1][3])
    float b2[3] = {q0.z, q0.w, q1.x};
#pragma unroll
    for (int i = 0; i < 3; ++i) {
        float by = Y0 * b2[i];
        ox = fmaf(by, cg[10 + i * 3 + 0], ox);
        oy = fmaf(by, cg[10 + i * 3 + 1], oy);
        oz = fmaf(by, cg[10 + i * 3 + 2], oz);
    }
    // P4: out1[m] += sum_{i,j} b4[i] * Y2v[j] * cg4[(i*5+j)*3+m]  (offset 28, [3][5][3])
    float b4[3] = {q2.x, q2.y, q2.z};
#pragma unroll
    for (int i = 0; i < 3; ++i) {
#pragma unroll
        for (int j = 0; j < 5; ++j) {
            float ay = b4[i] * Y2v[j];
            const float* cc = cg + 28 + (i * 5 + j) * 3;
            ox = fmaf(cc[0], ay, ox);
            oy = fmaf(cc[1], ay, oy);
            oz = fmaf(cc[2], ay, oz);
        }
    }
    float* ob = out + (size_t)dst * 128;
    unsafeAtomicAdd(ob + w, o0);
    float* o1p = ob + 32 + w * 3;
    unsafeAtomicAdd(o1p + 0, ox);
    unsafeAtomicAdd(o1p + 1, oy);
    unsafeAtomicAdd(o1p + 2, oz);
}

extern "C" void kernel_launch(void* const* d_in, const int* in_sizes, int n_in,
                              void* d_out, int out_size, void* d_ws, size_t ws_size,
                              hipStream_t stream) {
    const float* feat = (const float*)d_in[0];
    const float* sh = (const float*)d_in[1];
    const int* eidx = (const int*)d_in[2];
    const float* W = (const float*)d_in[3];
    float* out = (float*)d_out;
    int N = in_sizes[0] / 128;
    int E = in_sizes[1] / 9;

    float* wsf = (float*)d_ws;
    float* cg = wsf;
    float* T = wsf + WS_T_OFF;

    cg_init_kernel<<<1, 1, 0, stream>>>(cg);
    int nthreads = N * 32;
    node_precompute<<<(nthreads + 255) / 256, 256, 0, stream>>>(feat, W, T, N);
    hipMemsetAsync(d_out, 0, (size_t)out_size * sizeof(float), stream);
    int ethreads = E * 32;
    edge_kernel<<<(ethreads + 255) / 256, 256, 0, stream>>>(T, sh, eidx, cg, out, E);
}

// Round 3
// 475.640 us; speedup vs baseline: 2.5607x; 2.5607x over previous
//
#include <hip/hip_runtime.h>
#include <math.h>

// ---------------------------------------------------------------------------
// Workspace layout (4B units):
//   cg      : floats [0..128)          CG tensors (alpha/norm folded)
//             P0 @0 (1), P1 @1 (1x3x3), P2 @10 (3x1x3), P3 @19 (3x3x1), P4 @28 (3x5x3)
//   cursor  : ints   [128 .. 128+N)    histogram -> prefix -> running cursor -> row ends
//   eorder  : ints   [.. +E)           edge ids sorted by dst
//   T       : floats (16B aligned)     node precompute [N][32][12]
// ---------------------------------------------------------------------------

__device__ inline double dfact(int n) {
    double r = 1.0;
    for (int i = 2; i <= n; ++i) r *= (double)i;
    return r;
}

// real->complex spherical harmonic change of basis (e3nn convention)
__device__ void qmat(int l, double qr[5][5], double qi[5][5]) {
    for (int a = 0; a < 5; a++)
        for (int b = 0; b < 5; b++) { qr[a][b] = 0.0; qi[a][b] = 0.0; }
    const double inv = 0.70710678118654752440;
    for (int m = -l; m < 0; ++m) {
        qr[l + m][l - m] = inv;
        qi[l + m][l + m] = -inv;
    }
    qr[l][l] = 1.0;
    for (int m = 1; m <= l; ++m) {
        double sgn = (m & 1) ? -1.0 : 1.0;
        qr[l + m][l + m] = sgn * inv;
        qi[l + m][l - m] = sgn * inv;
    }
    if (l == 1) {          // * (-i)
        for (int a = 0; a < 5; a++)
            for (int b = 0; b < 5; b++) {
                double r = qr[a][b], im = qi[a][b];
                qr[a][b] = im; qi[a][b] = -r;
            }
    } else if (l == 2) {   // * (-1)
        for (int a = 0; a < 5; a++)
            for (int b = 0; b < 5; b++) { qr[a][b] = -qr[a][b]; qi[a][b] = -qi[a][b]; }
    }
}

// SU(2) "CG" single element via the reference's exact Racah-form (all six
// m-dependent factorials in the NUMERATOR — non-standard but matches ref).
__device__ double su2_cg_elem(int l1, int l2, int l3, int i, int k, int n) {
    int m1 = i - l1, m2 = k - l2, m3 = n - l3;
    if (m1 + m2 != m3) return 0.0;
    int vmin = -l1 + l2 + m3;
    if (-l1 + m1 > vmin) vmin = -l1 + m1;
    if (0 > vmin) vmin = 0;
    int vmax = l2 + l3 + m1;
    if (l3 - l1 + l2 < vmax) vmax = l3 - l1 + l2;
    if (l3 + m3 < vmax) vmax = l3 + m3;
    if (vmax < vmin) return 0.0;
    double c = sqrt((double)(2 * l3 + 1) * dfact(l3 + l1 - l2) *
                    dfact(l3 - l1 + l2) * dfact(l1 + l2 - l3) /
                    dfact(l1 + l2 + l3 + 1));
    c *= sqrt(dfact(l3 + m3) * dfact(l3 - m3) * dfact(l1 - m1) *
              dfact(l1 + m1) * dfact(l2 - m2) * dfact(l2 + m2));
    double s = 0.0;
    for (int v = vmin; v <= vmax; ++v) {
        double term = dfact(l2 + l3 + m1 - v) * dfact(l1 - m1 + v) /
                      (dfact(v) * dfact(l3 - l1 + l2 - v) *
                       dfact(l3 + m3 - v) * dfact(v + l1 - l2 - m3));
        if ((v + l2 + m2) & 1) term = -term;
        s += term;
    }
    return c * s;
}

// Parallel CG init: thread t -> (path p = t/45, element idx = t%45).
__global__ void cg_init_kernel(float* __restrict__ cg_out) {
    const int l1s[5] = {0, 0, 1, 1, 1};
    const int l2s[5] = {0, 1, 0, 1, 2};
    const int l3s[5] = {0, 1, 1, 0, 1};
    const int offs[5] = {0, 1, 10, 19, 28};
    const double alphas[5] = {0.125, 0.10206207261596575, 0.10206207261596575,
                              0.125, 0.10206207261596575};
    __shared__ double vals[5][45];
    int t = threadIdx.x;
    int p = t / 45, idx = t % 45;
    bool active = (t < 225);
    double acc = 0.0;
    int d1 = 0, d2 = 0, d3 = 0;
    if (active) {
        int l1 = l1s[p], l2 = l2s[p], l3 = l3s[p];
        d1 = 2 * l1 + 1; d2 = 2 * l2 + 1; d3 = 2 * l3 + 1;
        if (idx < d1 * d2 * d3) {
            int j = idx / (d2 * d3);
            int rem = idx % (d2 * d3);
            int l_ = rem / d3, m = rem % d3;
            double q1r[5][5], q1i[5][5], q2r[5][5], q2i[5][5], q3r[5][5], q3i[5][5];
            qmat(l1, q1r, q1i);
            qmat(l2, q2r, q2i);
            qmat(l3, q3r, q3i);
            for (int i = 0; i < d1; ++i)
                for (int k = 0; k < d2; ++k)
                    for (int n = 0; n < d3; ++n) {
                        double C = su2_cg_elem(l1, l2, l3, i, k, n);
                        if (C == 0.0) continue;
                        double ar = q1r[i][j], ai = q1i[i][j];
                        double br = q2r[k][l_], bi = q2i[k][l_];
                        double cr = q3r[n][m], ci = q3i[n][m];
                        double abr = ar * br - ai * bi;
                        double abi = ar * bi + ai * br;
                        acc += (abr * cr + abi * ci) * C;  // Re(a*b*conj(c))
                    }
        }
        vals[p][idx] = acc;
    }
    __syncthreads();
    if (active && idx < d1 * d2 * d3) {
        double n2 = 0.0;
        for (int q = 0; q < 45; ++q) n2 += vals[p][q] * vals[p][q];
        cg_out[offs[p] + idx] = (float)(acc * alphas[p] / sqrt(n2));
    }
}

// ---------------------------------------------------------------------------
// Node precompute: T[n][w][12] = {a0, a1, b2[0..2], b3[0..2], b4[0..2], pad}
// ---------------------------------------------------------------------------
__global__ __launch_bounds__(256) void node_precompute(
    const float* __restrict__ feat, const float* __restrict__ W,
    float* __restrict__ T, int N) {
    int t = blockIdx.x * 256 + threadIdx.x;
    int n = t >> 5, w = t & 31;
    if (n >= N) return;
    const float* f = feat + (size_t)n * 128;
    float a0 = 0.f, a1 = 0.f;
    float b2x = 0.f, b2y = 0.f, b2z = 0.f;
    float b3x = 0.f, b3y = 0.f, b3z = 0.f;
    float b4x = 0.f, b4y = 0.f, b4z = 0.f;
#pragma unroll 8
    for (int u = 0; u < 32; ++u) {
        float s = f[u];
        float v0 = f[32 + 3 * u], v1 = f[33 + 3 * u], v2 = f[34 + 3 * u];
        float w0 = W[u * 32 + w];
        float w1 = W[1024 + u * 32 + w];
        float w2 = W[2048 + u * 32 + w];
        float w3 = W[3072 + u * 32 + w];
        float w4 = W[4096 + u * 32 + w];
        a0 = fmaf(s, w0, a0);
        a1 = fmaf(s, w1, a1);
        b2x = fmaf(v0, w2, b2x); b2y = fmaf(v1, w2, b2y); b2z = fmaf(v2, w2, b2z);
        b3x = fmaf(v0, w3, b3x); b3y = fmaf(v1, w3, b3y); b3z = fmaf(v2, w3, b3z);
        b4x = fmaf(v0, w4, b4x); b4y = fmaf(v1, w4, b4y); b4z = fmaf(v2, w4, b4z);
    }
    float4* Tp = (float4*)(T + (size_t)(n * 32 + w) * 12);
    Tp[0] = make_float4(a0, a1, b2x, b2y);
    Tp[1] = make_float4(b2z, b3x, b3y, b3z);
    Tp[2] = make_float4(b4x, b4y, b4z, 0.f);
}

// ---------------------------------------------------------------------------
// CSR build: histogram -> block scan -> scatter
// ---------------------------------------------------------------------------
__global__ __launch_bounds__(256) void hist_kernel(
    const int* __restrict__ eidx, int* __restrict__ counts, int E) {
    int t = blockIdx.x * 256 + threadIdx.x;
    if (t >= E) return;
    atomicAdd(&counts[eidx[E + t]], 1);
}

// single block, 1024 threads: in-place exclusive prefix over cursor[0..N)
__global__ __launch_bounds__(1024) void scan_kernel(int* __restrict__ cursor, int N) {
    __shared__ int lds[1024];
    int tid = threadIdx.x;
    int C = (N + 1023) >> 10;
    int lo = tid * C, hi = lo + C;
    if (hi > N) hi = N;
    int sum = 0;
    for (int j = lo; j < hi; ++j) sum += cursor[j];
    lds[tid] = sum;
    __syncthreads();
    for (int off = 1; off < 1024; off <<= 1) {
        int v = 0;
        if (tid >= off) v = lds[tid - off];
        __syncthreads();
        if (tid >= off) lds[tid] += v;
        __syncthreads();
    }
    int prefix = (tid > 0) ? lds[tid - 1] : 0;
    for (int j = lo; j < hi; ++j) {
        int c = cursor[j];
        cursor[j] = prefix;
        prefix += c;
    }
}

__global__ __launch_bounds__(256) void scatter_kernel(
    const int* __restrict__ eidx, int* __restrict__ cursor,
    int* __restrict__ eorder, int E) {
    int t = blockIdx.x * 256 + threadIdx.x;
    if (t >= E) return;
    int pos = atomicAdd(&cursor[eidx[E + t]], 1);
    eorder[pos] = t;
}
// After scatter: cursor[d] == end of d's range; start(d) = d ? cursor[d-1] : 0.

// ---------------------------------------------------------------------------
// Gather kernel: one 64-lane wave per dst node. Lanes 0-31 process even
// edges, 32-63 odd edges (each lane owns output channel w = lane&31).
// Register accumulation, shfl_xor(32) combine, single clean write.
// ---------------------------------------------------------------------------
__global__ __launch_bounds__(256) void gather_kernel(
    const float* __restrict__ T, const float* __restrict__ sh,
    const int* __restrict__ eidx, const int* __restrict__ eorder,
    const int* __restrict__ cursor, const float* __restrict__ cg,
    float* __restrict__ out, int N, int E) {
    int wave = (blockIdx.x * 256 + threadIdx.x) >> 6;
    int lane = threadIdx.x & 63;
    if (wave >= N) return;
    int d = wave;
    int start = d ? cursor[d - 1] : 0;
    int end = cursor[d];
    int half = lane >> 5, w = lane & 31;

    float acc0 = 0.f, accx = 0.f, accy = 0.f, accz = 0.f;
    for (int idx = start + half; idx < end; idx += 2) {
        int e = eorder[idx];
        int src = eidx[e];
        const float4* Tp = (const float4*)(T + (size_t)(src * 32 + w) * 12);
        float4 q0 = Tp[0], q1 = Tp[1], q2 = Tp[2];
        const float* Ye = sh + (size_t)e * 9;
        float Y0 = Ye[0];
        float Y1v[3] = {Ye[1], Ye[2], Ye[3]};
        float Y2v[5] = {Ye[4], Ye[5], Ye[6], Ye[7], Ye[8]};

        // P0: out0 += cg0 * Y0 * a0
        acc0 = fmaf(cg[0] * Y0, q0.x, acc0);
        // P3: out0 += sum_{i,j} b3[i] * Y1v[j] * cg3[i*3+j]
        float b3[3] = {q1.y, q1.z, q1.w};
#pragma unroll
        for (int i = 0; i < 3; ++i)
#pragma unroll
            for (int j = 0; j < 3; ++j)
                acc0 = fmaf(b3[i] * Y1v[j], cg[19 + i * 3 + j], acc0);
        // P1: out1[m] += a1 * Y1v[j] * cg1[j*3+m]
#pragma unroll
        for (int j = 0; j < 3; ++j) {
            float ay = q0.y * Y1v[j];
            accx = fmaf(ay, cg[1 + j * 3 + 0], accx);
            accy = fmaf(ay, cg[1 + j * 3 + 1], accy);
            accz = fmaf(ay, cg[1 + j * 3 + 2], accz);
        }
        // P2: out1[m] += Y0 * b2[i] * cg2[i*3+m]
        float b2[3] = {q0.z, q0.w, q1.x};
#pragma unroll
        for (int i = 0; i < 3; ++i) {
            float by = Y0 * b2[i];
            accx = fmaf(by, cg[10 + i * 3 + 0], accx);
            accy = fmaf(by, cg[10 + i * 3 + 1], accy);
            accz = fmaf(by, cg[10 + i * 3 + 2], accz);
        }
        // P4: out1[m] += b4[i] * Y2v[j] * cg4[(i*5+j)*3+m]
        float b4[3] = {q2.x, q2.y, q2.z};
#pragma unroll
        for (int i = 0; i < 3; ++i) {
#pragma unroll
            for (int j = 0; j < 5; ++j) {
                float ay = b4[i] * Y2v[j];
                const float* cc = cg + 28 + (i * 5 + j) * 3;
                accx = fmaf(cc[0], ay, accx);
                accy = fmaf(cc[1], ay, accy);
                accz = fmaf(cc[2], ay, accz);
            }
        }
    }
    acc0 += __shfl_xor(acc0, 32);
    accx += __shfl_xor(accx, 32);
    accy += __shfl_xor(accy, 32);
    accz += __shfl_xor(accz, 32);
    if (half == 0) {
        float* ob = out + (size_t)d * 128;
        ob[w] = acc0;
        float* o1p = ob + 32 + w * 3;
        o1p[0] = accx;
        o1p[1] = accy;
        o1p[2] = accz;
    }
}

extern "C" void kernel_launch(void* const* d_in, const int* in_sizes, int n_in,
                              void* d_out, int out_size, void* d_ws, size_t ws_size,
                              hipStream_t stream) {
    const float* feat = (const float*)d_in[0];
    const float* sh = (const float*)d_in[1];
    const int* eidx = (const int*)d_in[2];
    const float* W = (const float*)d_in[3];
    float* out = (float*)d_out;
    int N = in_sizes[0] / 128;
    int E = in_sizes[1] / 9;

    float* wsf = (float*)d_ws;
    float* cg = wsf;
    int* cursor = (int*)(wsf + 128);
    int* eorder = cursor + N;
    size_t toff = 128 + (size_t)N + (size_t)E;
    toff = (toff + 3) & ~(size_t)3;
    float* T = wsf + toff;

    cg_init_kernel<<<1, 256, 0, stream>>>(cg);
    node_precompute<<<(N * 32 + 255) / 256, 256, 0, stream>>>(feat, W, T, N);
    hipMemsetAsync(cursor, 0, (size_t)N * sizeof(int), stream);
    hist_kernel<<<(E + 255) / 256, 256, 0, stream>>>(eidx, cursor, E);
    scan_kernel<<<1, 1024, 0, stream>>>(cursor, N);
    scatter_kernel<<<(E + 255) / 256, 256, 0, stream>>>(eidx, cursor, eorder, E);
    int gblocks = (N * 64 + 255) / 256;
    gather_kernel<<<gblocks, 256, 0, stream>>>(T, sh, eidx, eorder, cursor, cg, out, N, E);
}

// Round 4
// 289.228 us; speedup vs baseline: 4.2111x; 1.6445x over previous
//
#include <hip/hip_runtime.h>
#include <math.h>

// ---------------------------------------------------------------------------
// Workspace layout (4B words):
//   cg       [0..128)                  CG tensors (alpha/norm folded)
//   cursor   [128 .. 128+N)            hist -> prefix -> cursor -> row ends
//   tilesums [128+N .. 128+N+256)      per-tile sums for hierarchical scan
//   sE       [.. +E*10)                dst-sorted edge records, 40 B each:
//                                      {src:int, 9x uint bf16x2 = 17 Z values}
//   Tb       [.. +N*192)               node table bf16: [N][32][6] uints (24 B/lane)
// ---------------------------------------------------------------------------

__device__ inline float blo(unsigned u) { return __uint_as_float(u << 16); }
__device__ inline float bhi(unsigned u) { return __uint_as_float(u & 0xffff0000u); }
__device__ inline unsigned bpack(float a, float b) {
    unsigned ua = __float_as_uint(a);
    ua = (ua + 0x7fffu + ((ua >> 16) & 1u)) >> 16;
    unsigned ub = __float_as_uint(b);
    ub = (ub + 0x7fffu + ((ub >> 16) & 1u)) & 0xffff0000u;
    return ua | ub;
}

__device__ inline double dfact(int n) {
    double r = 1.0;
    for (int i = 2; i <= n; ++i) r *= (double)i;
    return r;
}

// real->complex spherical harmonic change of basis (e3nn convention)
__device__ void qmat(int l, double qr[5][5], double qi[5][5]) {
    for (int a = 0; a < 5; a++)
        for (int b = 0; b < 5; b++) { qr[a][b] = 0.0; qi[a][b] = 0.0; }
    const double inv = 0.70710678118654752440;
    for (int m = -l; m < 0; ++m) {
        qr[l + m][l - m] = inv;
        qi[l + m][l + m] = -inv;
    }
    qr[l][l] = 1.0;
    for (int m = 1; m <= l; ++m) {
        double sgn = (m & 1) ? -1.0 : 1.0;
        qr[l + m][l + m] = sgn * inv;
        qi[l + m][l - m] = sgn * inv;
    }
    if (l == 1) {          // * (-i)
        for (int a = 0; a < 5; a++)
            for (int b = 0; b < 5; b++) {
                double r = qr[a][b], im = qi[a][b];
                qr[a][b] = im; qi[a][b] = -r;
            }
    } else if (l == 2) {   // * (-1)
        for (int a = 0; a < 5; a++)
            for (int b = 0; b < 5; b++) { qr[a][b] = -qr[a][b]; qi[a][b] = -qi[a][b]; }
    }
}

// SU(2) "CG" element via the reference's exact Racah-form (all six m-dependent
// factorials in the NUMERATOR — non-standard but matches the reference).
__device__ double su2_cg_elem(int l1, int l2, int l3, int i, int k, int n) {
    int m1 = i - l1, m2 = k - l2, m3 = n - l3;
    if (m1 + m2 != m3) return 0.0;
    int vmin = -l1 + l2 + m3;
    if (-l1 + m1 > vmin) vmin = -l1 + m1;
    if (0 > vmin) vmin = 0;
    int vmax = l2 + l3 + m1;
    if (l3 - l1 + l2 < vmax) vmax = l3 - l1 + l2;
    if (l3 + m3 < vmax) vmax = l3 + m3;
    if (vmax < vmin) return 0.0;
    double c = sqrt((double)(2 * l3 + 1) * dfact(l3 + l1 - l2) *
                    dfact(l3 - l1 + l2) * dfact(l1 + l2 - l3) /
                    dfact(l1 + l2 + l3 + 1));
    c *= sqrt(dfact(l3 + m3) * dfact(l3 - m3) * dfact(l1 - m1) *
              dfact(l1 + m1) * dfact(l2 - m2) * dfact(l2 + m2));
    double s = 0.0;
    for (int v = vmin; v <= vmax; ++v) {
        double term = dfact(l2 + l3 + m1 - v) * dfact(l1 - m1 + v) /
                      (dfact(v) * dfact(l3 - l1 + l2 - v) *
                       dfact(l3 + m3 - v) * dfact(v + l1 - l2 - m3));
        if ((v + l2 + m2) & 1) term = -term;
        s += term;
    }
    return c * s;
}

// Parallel CG init: thread t -> (path p = t/45, element idx = t%45).
__global__ void cg_init_kernel(float* __restrict__ cg_out) {
    const int l1s[5] = {0, 0, 1, 1, 1};
    const int l2s[5] = {0, 1, 0, 1, 2};
    const int l3s[5] = {0, 1, 1, 0, 1};
    const int offs[5] = {0, 1, 10, 19, 28};
    const double alphas[5] = {0.125, 0.10206207261596575, 0.10206207261596575,
                              0.125, 0.10206207261596575};
    __shared__ double vals[5][45];
    int t = threadIdx.x;
    int p = t / 45, idx = t % 45;
    bool active = (t < 225);
    double acc = 0.0;
    int d1 = 0, d2 = 0, d3 = 0;
    if (active) {
        int l1 = l1s[p], l2 = l2s[p], l3 = l3s[p];
        d1 = 2 * l1 + 1; d2 = 2 * l2 + 1; d3 = 2 * l3 + 1;
        if (idx < d1 * d2 * d3) {
            int j = idx / (d2 * d3);
            int rem = idx % (d2 * d3);
            int l_ = rem / d3, m = rem % d3;
            double q1r[5][5], q1i[5][5], q2r[5][5], q2i[5][5], q3r[5][5], q3i[5][5];
            qmat(l1, q1r, q1i);
            qmat(l2, q2r, q2i);
            qmat(l3, q3r, q3i);
            for (int i = 0; i < d1; ++i)
                for (int k = 0; k < d2; ++k)
                    for (int n = 0; n < d3; ++n) {
                        double C = su2_cg_elem(l1, l2, l3, i, k, n);
                        if (C == 0.0) continue;
                        double ar = q1r[i][j], ai = q1i[i][j];
                        double br = q2r[k][l_], bi = q2i[k][l_];
                        double cr = q3r[n][m], ci = q3i[n][m];
                        double abr = ar * br - ai * bi;
                        double abi = ar * bi + ai * br;
                        acc += (abr * cr + abi * ci) * C;  // Re(a*b*conj(c))
                    }
        }
        vals[p][idx] = acc;
    }
    __syncthreads();
    if (active && idx < d1 * d2 * d3) {
        double n2 = 0.0;
        for (int q = 0; q < 45; ++q) n2 += vals[p][q] * vals[p][q];
        cg_out[offs[p] + idx] = (float)(acc * alphas[p] / sqrt(n2));
    }
}

// ---------------------------------------------------------------------------
// Node precompute -> bf16 table Tb[n][w][6] uints (bf16x2):
//   u0={a0,a1} u1={b2x,b2y} u2={b2z,b3x} u3={b3y,b3z} u4={b4x,b4y} u5={b4z,0}
// ---------------------------------------------------------------------------
__global__ __launch_bounds__(256) void node_precompute(
    const float* __restrict__ feat, const float* __restrict__ W,
    unsigned* __restrict__ Tb, int N) {
    int t = blockIdx.x * 256 + threadIdx.x;
    int n = t >> 5, w = t & 31;
    if (n >= N) return;
    const float* f = feat + (size_t)n * 128;
    float a0 = 0.f, a1 = 0.f;
    float b2x = 0.f, b2y = 0.f, b2z = 0.f;
    float b3x = 0.f, b3y = 0.f, b3z = 0.f;
    float b4x = 0.f, b4y = 0.f, b4z = 0.f;
#pragma unroll 8
    for (int u = 0; u < 32; ++u) {
        float s = f[u];
        float v0 = f[32 + 3 * u], v1 = f[33 + 3 * u], v2 = f[34 + 3 * u];
        float w0 = W[u * 32 + w];
        float w1 = W[1024 + u * 32 + w];
        float w2 = W[2048 + u * 32 + w];
        float w3 = W[3072 + u * 32 + w];
        float w4 = W[4096 + u * 32 + w];
        a0 = fmaf(s, w0, a0);
        a1 = fmaf(s, w1, a1);
        b2x = fmaf(v0, w2, b2x); b2y = fmaf(v1, w2, b2y); b2z = fmaf(v2, w2, b2z);
        b3x = fmaf(v0, w3, b3x); b3y = fmaf(v1, w3, b3y); b3z = fmaf(v2, w3, b3z);
        b4x = fmaf(v0, w4, b4x); b4y = fmaf(v1, w4, b4y); b4z = fmaf(v2, w4, b4z);
    }
    unsigned* Tp = Tb + (size_t)(n * 32 + w) * 6;
    Tp[0] = bpack(a0, a1);
    Tp[1] = bpack(b2x, b2y);
    Tp[2] = bpack(b2z, b3x);
    Tp[3] = bpack(b3y, b3z);
    Tp[4] = bpack(b4x, b4y);
    Tp[5] = bpack(b4z, 0.f);
}

// ---------------------------------------------------------------------------
// CSR build: histogram -> 3-pass coalesced scan -> scatter(+Z precompute)
// ---------------------------------------------------------------------------
__global__ __launch_bounds__(256) void hist_kernel(
    const int* __restrict__ eidx, int* __restrict__ counts, int E) {
    int t = blockIdx.x * 256 + threadIdx.x;
    if (t >= E) return;
    atomicAdd(&counts[eidx[E + t]], 1);
}

__global__ __launch_bounds__(256) void scanA_kernel(
    const int* __restrict__ counts, int* __restrict__ tilesums, int N) {
    __shared__ int lds[4];
    int i = blockIdx.x * 256 + threadIdx.x;
    int v = (i < N) ? counts[i] : 0;
#pragma unroll
    for (int d = 1; d < 64; d <<= 1) v += __shfl_xor(v, d);
    int wid = threadIdx.x >> 6;
    if ((threadIdx.x & 63) == 0) lds[wid] = v;
    __syncthreads();
    if (threadIdx.x == 0)
        tilesums[blockIdx.x] = lds[0] + lds[1] + lds[2] + lds[3];
}

// exclusive scan of tilesums (tiles <= 256), single block of 256
__global__ __launch_bounds__(256) void scanB_kernel(
    int* __restrict__ tilesums, int tiles) {
    __shared__ int lds[4];
    int tid = threadIdx.x;
    int v = (tid < tiles) ? tilesums[tid] : 0;
    int orig = v;
#pragma unroll
    for (int d = 1; d < 64; d <<= 1) {
        int t = __shfl_up(v, d);
        if ((tid & 63) >= d) v += t;
    }
    int wid = tid >> 6;
    if ((tid & 63) == 63) lds[wid] = v;
    __syncthreads();
    int base = 0;
    for (int q = 0; q < wid; ++q) base += lds[q];
    if (tid < tiles) tilesums[tid] = base + v - orig;  // exclusive
}

__global__ __launch_bounds__(256) void scanC_kernel(
    int* __restrict__ counts, const int* __restrict__ tilesums, int N) {
    __shared__ int lds[4];
    int i = blockIdx.x * 256 + threadIdx.x;
    int tid = threadIdx.x;
    int v = (i < N) ? counts[i] : 0;
    int orig = v;
#pragma unroll
    for (int d = 1; d < 64; d <<= 1) {
        int t = __shfl_up(v, d);
        if ((tid & 63) >= d) v += t;
    }
    int wid = tid >> 6;
    if ((tid & 63) == 63) lds[wid] = v;
    __syncthreads();
    int base = tilesums[blockIdx.x];
    for (int q = 0; q < wid; ++q) base += lds[q];
    if (i < N) counts[i] = base + v - orig;  // exclusive prefix
}

// scatter: per edge, compute the 17 lane-invariant Z values (CG (x) Y folded),
// pack to bf16, and write one 40B record at the dst-sorted position.
// Record: word0 = src; words1..9 = bf16x2:
//   h0=Z0 h1=Y0 | h2..4=Z1[m] | h5..7=Z3[i] | h8..16=Z4[i*3+m] | h17=0
__global__ __launch_bounds__(256) void scatter_kernel(
    const int* __restrict__ eidx, const float* __restrict__ sh,
    const float* __restrict__ cg, int* __restrict__ cursor,
    unsigned* __restrict__ sE, int E) {
    int t = blockIdx.x * 256 + threadIdx.x;
    if (t >= E) return;
    int src = eidx[t];
    int dst = eidx[E + t];
    int pos = atomicAdd(&cursor[dst], 1);
    const float* Ye = sh + (size_t)t * 9;
    float Y0 = Ye[0];
    float Y1v[3] = {Ye[1], Ye[2], Ye[3]};
    float Y2v[5] = {Ye[4], Ye[5], Ye[6], Ye[7], Ye[8]};
    float Z0 = cg[0] * Y0;
    float Z1[3], Z3[3], Z4[9];
#pragma unroll
    for (int m = 0; m < 3; ++m)
        Z1[m] = fmaf(Y1v[0], cg[1 + m],
                fmaf(Y1v[1], cg[4 + m], Y1v[2] * cg[7 + m]));
#pragma unroll
    for (int i = 0; i < 3; ++i)
        Z3[i] = fmaf(Y1v[0], cg[19 + i * 3],
                fmaf(Y1v[1], cg[19 + i * 3 + 1], Y1v[2] * cg[19 + i * 3 + 2]));
#pragma unroll
    for (int i = 0; i < 3; ++i)
#pragma unroll
        for (int m = 0; m < 3; ++m) {
            float acc = 0.f;
#pragma unroll
            for (int j = 0; j < 5; ++j)
                acc = fmaf(Y2v[j], cg[28 + (i * 5 + j) * 3 + m], acc);
            Z4[i * 3 + m] = acc;
        }
    unsigned* rec = sE + (size_t)pos * 10;
    rec[0] = (unsigned)src;
    rec[1] = bpack(Z0, Y0);
    rec[2] = bpack(Z1[0], Z1[1]);
    rec[3] = bpack(Z1[2], Z3[0]);
    rec[4] = bpack(Z3[1], Z3[2]);
    rec[5] = bpack(Z4[0], Z4[1]);
    rec[6] = bpack(Z4[2], Z4[3]);
    rec[7] = bpack(Z4[4], Z4[5]);
    rec[8] = bpack(Z4[6], Z4[7]);
    rec[9] = bpack(Z4[8], 0.f);
}
// After scatter: cursor[d] == end of d's range; start(d) = d ? cursor[d-1] : 0.

// ---------------------------------------------------------------------------
// Gather: one 64-lane wave per dst. Half-waves process alternate edges; lane
// owns channel w = lane&31. Sequential sE reads, random (coalesced) bf16 Tb
// reads, register accumulate, shfl_xor(32) combine, clean write.
// ---------------------------------------------------------------------------
__global__ __launch_bounds__(256) void gather_kernel(
    const unsigned* __restrict__ Tb, const unsigned* __restrict__ sE,
    const int* __restrict__ cursor, const float* __restrict__ cg,
    float* __restrict__ out, int N) {
    int wave = (blockIdx.x * 256 + threadIdx.x) >> 6;
    int lane = threadIdx.x & 63;
    if (wave >= N) return;
    int d = wave;
    int start = d ? cursor[d - 1] : 0;
    int end = cursor[d];
    int half = lane >> 5, w = lane & 31;

    // cg2 (P2 tensor) is uniform: hoist
    float c2[9];
#pragma unroll
    for (int k = 0; k < 9; ++k) c2[k] = cg[10 + k];

    float acc0 = 0.f, accx = 0.f, accy = 0.f, accz = 0.f;
    for (int idx = start + half; idx < end; idx += 2) {
        const uint2* e2 = (const uint2*)(sE + (size_t)idx * 10);
        uint2 p0 = e2[0], p1 = e2[1], p2 = e2[2], p3 = e2[3], p4 = e2[4];
        int src = (int)p0.x;
        const uint2* tp = (const uint2*)(Tb + (size_t)(src * 32 + w) * 6);
        uint2 A = tp[0], B = tp[1], C = tp[2];
        float a0 = blo(A.x), a1 = bhi(A.x);
        float b2x = blo(A.y), b2y = bhi(A.y);
        float b2z = blo(B.x), b3x = bhi(B.x);
        float b3y = blo(B.y), b3z = bhi(B.y);
        float b4x = blo(C.x), b4y = bhi(C.x), b4z = blo(C.y);

        float z0 = blo(p0.y), y0 = bhi(p0.y);
        float z10 = blo(p1.x), z11 = bhi(p1.x), z12 = blo(p1.y);
        float z30 = bhi(p1.y), z31 = blo(p2.x), z32 = bhi(p2.x);
        float z40 = blo(p2.y), z41 = bhi(p2.y), z42 = blo(p3.x);
        float z43 = bhi(p3.x), z44 = blo(p3.y), z45 = bhi(p3.y);
        float z46 = blo(p4.x), z47 = bhi(p4.x), z48 = blo(p4.y);

        // out0: P0 + P3
        acc0 = fmaf(z0, a0, acc0);
        acc0 = fmaf(b3x, z30, acc0);
        acc0 = fmaf(b3y, z31, acc0);
        acc0 = fmaf(b3z, z32, acc0);
        // out1: P1
        accx = fmaf(a1, z10, accx);
        accy = fmaf(a1, z11, accy);
        accz = fmaf(a1, z12, accz);
        // out1: P2 (rank-1: Y0 * b2[i] * cg2[i][m])
        float s0 = b2x * y0, s1 = b2y * y0, s2 = b2z * y0;
        accx = fmaf(s0, c2[0], fmaf(s1, c2[3], fmaf(s2, c2[6], accx)));
        accy = fmaf(s0, c2[1], fmaf(s1, c2[4], fmaf(s2, c2[7], accy)));
        accz = fmaf(s0, c2[2], fmaf(s1, c2[5], fmaf(s2, c2[8], accz)));
        // out1: P4
        accx = fmaf(b4x, z40, fmaf(b4y, z43, fmaf(b4z, z46, accx)));
        accy = fmaf(b4x, z41, fmaf(b4y, z44, fmaf(b4z, z47, accy)));
        accz = fmaf(b4x, z42, fmaf(b4y, z45, fmaf(b4z, z48, accz)));
    }
    acc0 += __shfl_xor(acc0, 32);
    accx += __shfl_xor(accx, 32);
    accy += __shfl_xor(accy, 32);
    accz += __shfl_xor(accz, 32);
    if (half == 0) {
        float* ob = out + (size_t)d * 128;
        ob[w] = acc0;
        float* o1p = ob + 32 + w * 3;
        o1p[0] = accx;
        o1p[1] = accy;
        o1p[2] = accz;
    }
}

extern "C" void kernel_launch(void* const* d_in, const int* in_sizes, int n_in,
                              void* d_out, int out_size, void* d_ws, size_t ws_size,
                              hipStream_t stream) {
    const float* feat = (const float*)d_in[0];
    const float* sh = (const float*)d_in[1];
    const int* eidx = (const int*)d_in[2];
    const float* W = (const float*)d_in[3];
    float* out = (float*)d_out;
    int N = in_sizes[0] / 128;
    int E = in_sizes[1] / 9;

    float* wsf = (float*)d_ws;
    float* cg = wsf;
    int* cursor = (int*)(wsf + 128);
    int* tilesums = cursor + N;
    unsigned* sE = (unsigned*)(tilesums + 256);
    unsigned* Tb = sE + (size_t)E * 10;

    int tiles = (N + 255) / 256;

    cg_init_kernel<<<1, 256, 0, stream>>>(cg);
    node_precompute<<<(N * 32 + 255) / 256, 256, 0, stream>>>(feat, W, Tb, N);
    hipMemsetAsync(cursor, 0, (size_t)N * sizeof(int), stream);
    hist_kernel<<<(E + 255) / 256, 256, 0, stream>>>(eidx, cursor, E);
    scanA_kernel<<<tiles, 256, 0, stream>>>(cursor, tilesums, N);
    scanB_kernel<<<1, 256, 0, stream>>>(tilesums, tiles);
    scanC_kernel<<<tiles, 256, 0, stream>>>(cursor, tilesums, N);
    scatter_kernel<<<(E + 255) / 256, 256, 0, stream>>>(eidx, sh, cg, cursor, sE, E);
    gather_kernel<<<(N * 64 + 255) / 256, 256, 0, stream>>>(Tb, sE, cursor, cg, out, N);
}